// Round 4
// baseline (481.610 us; speedup 1.0000x reference)
//
#include <hip/hip_runtime.h>
#include <hip/hip_bf16.h>

// CausalLocalAttention: B=4, S=4096, D=1024, H=16, DH=64, W=256 (16 windows)
// cvt_x -> cvt_wT -> gemm8<QKV fused, 256^2 4-phase/K-tile> -> attn(4096 blk) -> gemm8<O>

typedef __attribute__((ext_vector_type(4))) float f32x4;
typedef __attribute__((ext_vector_type(8))) short s16x8;
typedef __attribute__((ext_vector_type(4))) short s16x4;

__device__ __forceinline__ short f2bf(float f) {
  unsigned u = __float_as_uint(f);
  u += 0x7fffu + ((u >> 16) & 1u);   // RNE
  return (short)(u >> 16);
}

__device__ __forceinline__ void gload_lds16(const void* g, void* l) {
  __builtin_amdgcn_global_load_lds((const __attribute__((address_space(1))) void*)g,
                                   (__attribute__((address_space(3))) void*)l,
                                   16, 0, 0);
}

__device__ __forceinline__ float rmax16(float v) {
  v = fmaxf(v, __shfl_xor(v, 1, 64));
  v = fmaxf(v, __shfl_xor(v, 2, 64));
  v = fmaxf(v, __shfl_xor(v, 4, 64));
  v = fmaxf(v, __shfl_xor(v, 8, 64));
  return v;
}
__device__ __forceinline__ float rsum16(float v) {
  v += __shfl_xor(v, 1, 64);
  v += __shfl_xor(v, 2, 64);
  v += __shfl_xor(v, 4, 64);
  v += __shfl_xor(v, 8, 64);
  return v;
}

// ---------------- convert x (fp32 -> bf16) ----------------
__global__ void cvt_x(const float4* __restrict__ in, s16x4* __restrict__ out, int n4) {
  for (int i = blockIdx.x * 256 + threadIdx.x; i < n4; i += gridDim.x * 256) {
    float4 v = in[i];
    s16x4 o;
    o[0] = f2bf(v.x); o[1] = f2bf(v.y); o[2] = f2bf(v.z); o[3] = f2bf(v.w);
    out[i] = o;
  }
}

// ------------- convert + transpose weights: W[k][n] fp32 -> Wt[n][k] bf16 -------------
__global__ void cvt_wT(const float* __restrict__ W0, const float* __restrict__ W1,
                       const float* __restrict__ W2, const float* __restrict__ W3,
                       short* __restrict__ out) {
  __shared__ float tile[64][65];
  const float* W = (blockIdx.y == 0) ? W0 : (blockIdx.y == 1) ? W1 : (blockIdx.y == 2) ? W2 : W3;
  short* o = out + (size_t)blockIdx.y * (1024 * 1024);
  const int kt = (blockIdx.x >> 4) << 6, nt = (blockIdx.x & 15) << 6;
  const int tid = threadIdx.x;
#pragma unroll
  for (int i = 0; i < 16; ++i) {
    int lin = i * 256 + tid;
    int r = lin >> 6, c = lin & 63;
    tile[r][c] = W[(size_t)(kt + r) * 1024 + nt + c];
  }
  __syncthreads();
#pragma unroll
  for (int i = 0; i < 16; ++i) {
    int lin = i * 256 + tid;
    int r = lin >> 6, c = lin & 63;
    o[(size_t)(nt + r) * 1024 + kt + c] = f2bf(tile[c][r]);
  }
}

// ======== 256x256 GEMM, BK=64, 8 waves, 4-phase/K-tile, XOR-swizzled LDS ========
// C[M, NBN*256] = A[M,1024](bf16) x Bt[n][k]^T + bias
// MODE 0: fused QKV bf16 scatter (n block 0..3: Q [B,H,S,DH]; K same; Vt [B,H,DH,S])
// MODE 2: fp32 [M,1024] out (O projection)
// LDS swizzle: byte ^= (row&7)<<4 (both-sides: pre-swizzled global src + swz read)
template <int NBN, int MODE>
__global__ __launch_bounds__(512, 2) void gemm8(const short* __restrict__ A,
                                                const short* __restrict__ BtBase,
                                                const float* __restrict__ b0,
                                                const float* __restrict__ b1,
                                                const float* __restrict__ b2,
                                                short* __restrict__ Qo,
                                                short* __restrict__ Ko,
                                                short* __restrict__ Vo,
                                                float* __restrict__ Oo) {
  __shared__ short As[2][16384];   // [256 rows][64 k] bf16, dbuf  (32 KB x2)
  __shared__ short Bs[2][16384];   //                              (32 KB x2) = 128 KiB
  const int tid = threadIdx.x;
  const int wid = tid >> 6, lane = tid & 63;
  const int fr = lane & 15, g = lane >> 4;
  const int wr = wid >> 2, wc = wid & 3;          // 2x4 wave grid; wave tile 128x64
  const int fswz = (fr & 7) << 4;
  // chunked XCD swizzle: xcd = blockIdx%8 owns contiguous bm chunk
  const int d = blockIdx.x;
  const int xcd = d & 7, l = d >> 3;
  const int bm = xcd * 8 + l / NBN, bn = l % NBN;
  const int m0 = bm << 8, n0 = bn << 8;
  const int which = n0 >> 10;                     // uniform per block
  const char* Ab = (const char*)(A + (size_t)m0 * 1024);
  const char* Bb = (const char*)(BtBase + (size_t)which * 1048576 + (size_t)(n0 & 1023) * 1024);

  // staging geometry: instr i in 0..3, LDS linear L = i*8192 + tid*16
  // row = i*64 + tid/8, col_byte = (tid&7)*16; source col pre-swizzled
  const int srow = tid >> 3;
  const int kb = ((tid & 7) << 4) ^ ((srow & 7) << 4);
  const char* aSrc = Ab + (size_t)srow * 2048 + kb;
  const char* bSrc = Bb + (size_t)srow * 2048 + kb;
  const int ldsOff = wid << 10;                   // wave-uniform byte base (+ lane*16 by HW)

#define STAGE2(srcp, dstp, i0, tt)                                            \
  do {                                                                        \
    gload_lds16((srcp) + (size_t)(i0) * 131072 + (size_t)(tt) * 128,          \
                (dstp) + (i0) * 8192 + ldsOff);                               \
    gload_lds16((srcp) + (size_t)((i0) + 1) * 131072 + (size_t)(tt) * 128,    \
                (dstp) + ((i0) + 1) * 8192 + ldsOff);                         \
  } while (0)

#define AFRAG(mi, ks) (*(const s16x8*)(Acur + ((((wr) << 7) + (mi) * 16 + fr) << 7) + \
                                       ((((ks) << 6) | (g << 4)) ^ fswz)))
#define BFRAG(ni, ks) (*(const s16x8*)(Bcur + ((((wc) << 6) + (ni) * 16 + fr) << 7) + \
                                       ((((ks) << 6) | (g << 4)) ^ fswz)))

#define PHASE_MID()                                       \
  __builtin_amdgcn_s_barrier();                           \
  asm volatile("s_waitcnt lgkmcnt(0)" ::: "memory");      \
  __builtin_amdgcn_sched_barrier(0);                      \
  __builtin_amdgcn_s_setprio(1)

#define PHASE_END()                                       \
  __builtin_amdgcn_s_setprio(0);                          \
  __builtin_amdgcn_s_barrier()

  f32x4 acc[8][4];
#pragma unroll
  for (int i = 0; i < 8; ++i)
#pragma unroll
    for (int j = 0; j < 4; ++j) acc[i][j] = (f32x4){0.f, 0.f, 0.f, 0.f};

  // prologue: stage K-tile 0 into slot 0
  {
    char* A0 = (char*)&As[0][0];
    char* B0 = (char*)&Bs[0][0];
    STAGE2(aSrc, A0, 0, 0); STAGE2(aSrc, A0, 2, 0);
    STAGE2(bSrc, B0, 0, 0); STAGE2(bSrc, B0, 2, 0);
  }

#pragma unroll 2
  for (int t = 0; t < 16; ++t) {
    const int cur = t & 1;
    const int tn = t + 1;
    const bool pre = (t < 15);                    // uniform
    const char* Acur = (const char*)&As[cur][0];
    const char* Bcur = (const char*)&Bs[cur][0];
    char* Anxt = (char*)&As[cur ^ 1][0];
    char* Bnxt = (char*)&Bs[cur ^ 1][0];

    asm volatile("s_waitcnt vmcnt(0)" ::: "memory");  // this tile's loads landed
    __builtin_amdgcn_s_barrier();

    s16x8 aF[2][4], bF0[2][2], bF1[2][2];
    // ---- P1: read A rows 0-63 (8) + B cols 0-31 (4); stage A(t+1) half 0 ----
#pragma unroll
    for (int ks = 0; ks < 2; ++ks) {
#pragma unroll
      for (int mi = 0; mi < 4; ++mi) aF[ks][mi] = AFRAG(mi, ks);
#pragma unroll
      for (int ni = 0; ni < 2; ++ni) bF0[ks][ni] = BFRAG(ni, ks);
    }
    if (pre) STAGE2(aSrc, Anxt, 0, tn);
    PHASE_MID();
#pragma unroll
    for (int ks = 0; ks < 2; ++ks)
#pragma unroll
      for (int mi = 0; mi < 4; ++mi)
#pragma unroll
        for (int ni = 0; ni < 2; ++ni)
          acc[mi][ni] = __builtin_amdgcn_mfma_f32_16x16x32_bf16(aF[ks][mi], bF0[ks][ni], acc[mi][ni], 0, 0, 0);
    PHASE_END();

    // ---- P2: read B cols 32-63 (4); stage A(t+1) half 1 ----
#pragma unroll
    for (int ks = 0; ks < 2; ++ks)
#pragma unroll
      for (int ni = 0; ni < 2; ++ni) bF1[ks][ni] = BFRAG(2 + ni, ks);
    if (pre) STAGE2(aSrc, Anxt, 2, tn);
    PHASE_MID();
#pragma unroll
    for (int ks = 0; ks < 2; ++ks)
#pragma unroll
      for (int mi = 0; mi < 4; ++mi)
#pragma unroll
        for (int ni = 0; ni < 2; ++ni)
          acc[mi][2 + ni] = __builtin_amdgcn_mfma_f32_16x16x32_bf16(aF[ks][mi], bF1[ks][ni], acc[mi][2 + ni], 0, 0, 0);
    PHASE_END();

    // ---- P3: read A rows 64-127 (8); stage B(t+1) half 0 ----
#pragma unroll
    for (int ks = 0; ks < 2; ++ks)
#pragma unroll
      for (int mi = 0; mi < 4; ++mi) aF[ks][mi] = AFRAG(4 + mi, ks);
    if (pre) STAGE2(bSrc, Bnxt, 0, tn);
    PHASE_MID();
#pragma unroll
    for (int ks = 0; ks < 2; ++ks)
#pragma unroll
      for (int mi = 0; mi < 4; ++mi)
#pragma unroll
        for (int ni = 0; ni < 2; ++ni)
          acc[4 + mi][2 + ni] = __builtin_amdgcn_mfma_f32_16x16x32_bf16(aF[ks][mi], bF1[ks][ni], acc[4 + mi][2 + ni], 0, 0, 0);
    PHASE_END();

    // ---- P4: no ds reads; stage B(t+1) half 1; reuse bF0 from P1 ----
    if (pre) STAGE2(bSrc, Bnxt, 2, tn);
    PHASE_MID();
#pragma unroll
    for (int ks = 0; ks < 2; ++ks)
#pragma unroll
      for (int mi = 0; mi < 4; ++mi)
#pragma unroll
        for (int ni = 0; ni < 2; ++ni)
          acc[4 + mi][ni] = __builtin_amdgcn_mfma_f32_16x16x32_bf16(aF[ks][mi], bF0[ks][ni], acc[4 + mi][ni], 0, 0, 0);
    PHASE_END();
  }
#undef STAGE2
#undef AFRAG
#undef BFRAG
#undef PHASE_MID
#undef PHASE_END

  // epilogue: D layout col=lane&15, row=(lane>>4)*4+reg  (m89-verified)
  const float* bb = (which == 0) ? b0 : (which == 1) ? b1 : b2;
  const int row0 = m0 + wr * 128 + (g << 2);
  const int col0 = n0 + wc * 64 + fr;
#pragma unroll
  for (int mi = 0; mi < 8; ++mi) {
#pragma unroll
    for (int ni = 0; ni < 4; ++ni) {
      const int c = col0 + ni * 16;
      const float bv = bb[c & 1023];
#pragma unroll
      for (int jj = 0; jj < 4; ++jj) {
        const int r = row0 + mi * 16 + jj;
        const float v = acc[mi][ni][jj] + bv;
        if (MODE == 2) {
          Oo[(size_t)r * 1024 + c] = v;
        } else {
          const int b = r >> 12, s = r & 4095;
          const int cl = c & 1023;
          const int h = cl >> 6, dh = cl & 63;
          short* ob = (which == 0) ? Qo : (which == 1) ? Ko : Vo;
          size_t addr;
          if (which < 2) addr = ((size_t)(b * 16 + h) * 4096 + s) * 64 + dh;
          else           addr = ((size_t)(b * 16 + h) * 64 + dh) * 4096 + s;
          ob[addr] = f2bf(v);
        }
      }
    }
  }
}

// ---------------- windowed causal attention ----------------
// grid = B*H*16*4 (window quarters); block = 256 (4 waves); wave w owns 16 q-rows
__global__ __launch_bounds__(256) void attn_kernel(const short* __restrict__ Qg,
                                                   const short* __restrict__ Kg,
                                                   const short* __restrict__ Vg,
                                                   short* __restrict__ AO) {
  constexpr int S = 4096;
  __shared__ short Pl[4][16][272];  // per-wave P tile, padded
  const int tid = threadIdx.x;
  const int w = tid >> 6, lane = tid & 63;
  const int fr = lane & 15, g = lane >> 4;
  const int idx = blockIdx.x;
  const int qq = idx & 3;
  const int nb = (idx >> 2) & 15, bh = idx >> 6;
  const int b = bh >> 4, h = bh & 15;
  const short* Qb = Qg + ((size_t)bh * S + nb * 256) * 64;
  const short* Kb = Kg + ((size_t)bh * S + nb * 256) * 64;
  const short* Vb = Vg + (size_t)bh * 64 * S + nb * 256;

  const int qrow = qq * 64 + w * 16;
  const int dmax = qq * 4 + w;  // diagonal 16-col tile (tiles 0..dmax active)
  const s16x8 aq0 = *(const s16x8*)&Qb[(qrow + fr) * 64 + (g << 3)];
  const s16x8 aq1 = *(const s16x8*)&Qb[(qrow + fr) * 64 + 32 + (g << 3)];
  f32x4 sc[16];
#pragma unroll
  for (int i = 0; i < 16; ++i) sc[i] = (f32x4){0.f, 0.f, 0.f, 0.f};
#pragma unroll
  for (int kt = 0; kt < 16; ++kt) {
    if (kt <= dmax) {
      const s16x8 kf0 = *(const s16x8*)&Kb[(kt * 16 + fr) * 64 + (g << 3)];
      const s16x8 kf1 = *(const s16x8*)&Kb[(kt * 16 + fr) * 64 + 32 + (g << 3)];
      sc[kt] = __builtin_amdgcn_mfma_f32_16x16x32_bf16(aq0, kf0, sc[kt], 0, 0, 0);
      sc[kt] = __builtin_amdgcn_mfma_f32_16x16x32_bf16(aq1, kf1, sc[kt], 0, 0, 0);
    }
  }
  float mrow[4] = {-3e38f, -3e38f, -3e38f, -3e38f};
#pragma unroll
  for (int kt = 0; kt < 16; ++kt) {
    if (kt <= dmax) {
#pragma unroll
      for (int jj = 0; jj < 4; ++jj) {
        float v = sc[kt][jj] * 0.125f;
        if (kt == dmax && fr > (g << 2) + jj) v = -3e38f;
        sc[kt][jj] = v;
        mrow[jj] = fmaxf(mrow[jj], v);
      }
    }
  }
#pragma unroll
  for (int jj = 0; jj < 4; ++jj) mrow[jj] = rmax16(mrow[jj]);
  float lsum[4] = {0.f, 0.f, 0.f, 0.f};
#pragma unroll
  for (int kt = 0; kt < 16; ++kt) {
    if (kt <= dmax) {
#pragma unroll
      for (int jj = 0; jj < 4; ++jj) {
        const float p = __expf(sc[kt][jj] - mrow[jj]);
        sc[kt][jj] = p;
        lsum[jj] += p;
      }
    }
  }
#pragma unroll
  for (int jj = 0; jj < 4; ++jj) lsum[jj] = rsum16(lsum[jj]);
  // P -> LDS (D-layout scatter), zero-fill odd trailing tile for 32-wide PV chunks
#pragma unroll
  for (int kt = 0; kt < 16; ++kt) {
    if (kt <= dmax) {
#pragma unroll
      for (int jj = 0; jj < 4; ++jj)
        Pl[w][(g << 2) + jj][kt * 16 + fr] = f2bf(sc[kt][jj]);
    } else if (kt == dmax + 1 && ((dmax + 1) & 1)) {
#pragma unroll
      for (int jj = 0; jj < 4; ++jj) Pl[w][(g << 2) + jj][kt * 16 + fr] = 0;
    }
  }
  asm volatile("s_waitcnt lgkmcnt(0)" ::: "memory");
  // PV: O[16q x 64dh] = P * V (Vt[dh][s], contiguous 16B per lane)
  f32x4 o[4];
#pragma unroll
  for (int di = 0; di < 4; ++di) o[di] = (f32x4){0.f, 0.f, 0.f, 0.f};
  const int nks2 = (dmax + 2) >> 1;
#pragma unroll
  for (int ks2 = 0; ks2 < 8; ++ks2) {
    if (ks2 < nks2) {
      const s16x8 pa = *(const s16x8*)&Pl[w][fr][ks2 * 32 + (g << 3)];
#pragma unroll
      for (int di = 0; di < 4; ++di) {
        const s16x8 vf = *(const s16x8*)&Vb[(size_t)(di * 16 + fr) * S + ks2 * 32 + (g << 3)];
        o[di] = __builtin_amdgcn_mfma_f32_16x16x32_bf16(pa, vf, o[di], 0, 0, 0);
      }
    }
  }
  float inv[4];
#pragma unroll
  for (int jj = 0; jj < 4; ++jj) inv[jj] = 1.f / lsum[jj];
  const int sg = nb * 256 + qrow + (g << 2);
#pragma unroll
  for (int di = 0; di < 4; ++di) {
#pragma unroll
    for (int jj = 0; jj < 4; ++jj) {
      AO[((size_t)b * S + sg + jj) * 1024 + h * 64 + di * 16 + fr] =
          f2bf(o[di][jj] * inv[jj]);
    }
  }
}

extern "C" void kernel_launch(void* const* d_in, const int* in_sizes, int n_in,
                              void* d_out, int out_size, void* d_ws, size_t ws_size,
                              hipStream_t stream) {
  const float* x  = (const float*)d_in[0];
  const float* Wq = (const float*)d_in[1];
  const float* bq = (const float*)d_in[2];
  const float* Wk = (const float*)d_in[3];
  const float* bk = (const float*)d_in[4];
  const float* Wv = (const float*)d_in[5];
  const float* bv = (const float*)d_in[6];
  const float* Wo = (const float*)d_in[7];
  const float* bo = (const float*)d_in[8];
  float* out = (float*)d_out;

  char* ws = (char*)d_ws;
  short* xb  = (short*)ws;                                   // 32 MB  bf16 x [16384,1024]
  short* Wt  = (short*)(ws + (size_t)33554432);              // 8 MB   Wt q/k/v/o [1024,1024] each
  short* Qb  = (short*)(ws + (size_t)33554432 + 8388608);    // 32 MB  [B,H,S,DH]
  short* Kb  = Qb + (size_t)16777216;                        // 32 MB  [B,H,S,DH]
  short* Vb  = Kb + (size_t)16777216;                        // 32 MB  [B,H,DH,S]
  short* AOb = Vb + (size_t)16777216;                        // 32 MB  [B*S, D]

  cvt_x<<<4096, 256, 0, stream>>>((const float4*)x, (s16x4*)xb, 16777216 / 4);
  cvt_wT<<<dim3(256, 4), 256, 0, stream>>>(Wq, Wk, Wv, Wo, Wt);

  // fused QKV: grid = 64 bm * 12 bn = 768 (%8==0)
  gemm8<12, 0><<<768, 512, 0, stream>>>(xb, Wt, bq, bk, bv, Qb, Kb, Vb, nullptr);

  attn_kernel<<<4096, 256, 0, stream>>>(Qb, Kb, Vb, AOb);

  // O projection: grid = 64 bm * 4 bn = 256 (%8==0)
  gemm8<4, 2><<<256, 512, 0, stream>>>(AOb, Wt + 3145728, bo, bo, bo,
                                       nullptr, nullptr, nullptr, out);
}

// Round 5
// 426.041 us; speedup vs baseline: 1.1304x; 1.1304x over previous
//
#include <hip/hip_runtime.h>
#include <hip/hip_bf16.h>

// CausalLocalAttention: B=4, S=4096, D=1024, H=16, DH=64, W=256 (16 windows)
// cvt_x -> cvt_wT -> gemm9<QKV fused, 256^2, counted vmcnt(8)> -> attn -> gemm9<O>

typedef __attribute__((ext_vector_type(4))) float f32x4;
typedef __attribute__((ext_vector_type(8))) short s16x8;
typedef __attribute__((ext_vector_type(4))) short s16x4;

__device__ __forceinline__ short f2bf(float f) {
  unsigned u = __float_as_uint(f);
  u += 0x7fffu + ((u >> 16) & 1u);   // RNE
  return (short)(u >> 16);
}

__device__ __forceinline__ void gload_lds16(const void* g, void* l) {
  __builtin_amdgcn_global_load_lds((const __attribute__((address_space(1))) void*)g,
                                   (__attribute__((address_space(3))) void*)l,
                                   16, 0, 0);
}

__device__ __forceinline__ float rmax16(float v) {
  v = fmaxf(v, __shfl_xor(v, 1, 64));
  v = fmaxf(v, __shfl_xor(v, 2, 64));
  v = fmaxf(v, __shfl_xor(v, 4, 64));
  v = fmaxf(v, __shfl_xor(v, 8, 64));
  return v;
}
__device__ __forceinline__ float rsum16(float v) {
  v += __shfl_xor(v, 1, 64);
  v += __shfl_xor(v, 2, 64);
  v += __shfl_xor(v, 4, 64);
  v += __shfl_xor(v, 8, 64);
  return v;
}

// ---------------- convert x (fp32 -> bf16) ----------------
__global__ void cvt_x(const float4* __restrict__ in, s16x4* __restrict__ out, int n4) {
  for (int i = blockIdx.x * 256 + threadIdx.x; i < n4; i += gridDim.x * 256) {
    float4 v = in[i];
    s16x4 o;
    o[0] = f2bf(v.x); o[1] = f2bf(v.y); o[2] = f2bf(v.z); o[3] = f2bf(v.w);
    out[i] = o;
  }
}

// ------------- convert + transpose weights: W[k][n] fp32 -> Wt[n][k] bf16 -------------
__global__ void cvt_wT(const float* __restrict__ W0, const float* __restrict__ W1,
                       const float* __restrict__ W2, const float* __restrict__ W3,
                       short* __restrict__ out) {
  __shared__ float tile[64][65];
  const float* W = (blockIdx.y == 0) ? W0 : (blockIdx.y == 1) ? W1 : (blockIdx.y == 2) ? W2 : W3;
  short* o = out + (size_t)blockIdx.y * (1024 * 1024);
  const int kt = (blockIdx.x >> 4) << 6, nt = (blockIdx.x & 15) << 6;
  const int tid = threadIdx.x;
#pragma unroll
  for (int i = 0; i < 16; ++i) {
    int lin = i * 256 + tid;
    int r = lin >> 6, c = lin & 63;
    tile[r][c] = W[(size_t)(kt + r) * 1024 + nt + c];
  }
  __syncthreads();
#pragma unroll
  for (int i = 0; i < 16; ++i) {
    int lin = i * 256 + tid;
    int r = lin >> 6, c = lin & 63;
    o[(size_t)(nt + r) * 1024 + kt + c] = f2bf(tile[c][r]);
  }
}

// ======== 256x256 GEMM, BK=64, 8 waves, counted vmcnt(8), XOR-swizzled LDS ========
// C[M, NBN*256] = A[M,1024](bf16) x Bt[n][k]^T + bias
// Per K-tile: STAGE(t+1) early -> vmcnt(8) -> barrier -> ds/MFMA (2 reg sub-phases,
// no mid barriers) -> lgkmcnt(0) -> barrier. Loads get a full tile to land.
// MODE 0: fused QKV bf16 scatter (Q/K [B,H,S,DH], Vt [B,H,DH,S]); MODE 2: fp32 out.
template <int NBN, int MODE>
__global__ __launch_bounds__(512, 2) void gemm9(const short* __restrict__ A,
                                                const short* __restrict__ BtBase,
                                                const float* __restrict__ b0,
                                                const float* __restrict__ b1,
                                                const float* __restrict__ b2,
                                                short* __restrict__ Qo,
                                                short* __restrict__ Ko,
                                                short* __restrict__ Vo,
                                                float* __restrict__ Oo) {
  __shared__ short As[2][16384];   // [256 rows][64 k] bf16, dbuf  (32 KB x2)
  __shared__ short Bs[2][16384];   //                              (32 KB x2) = 128 KiB
  const int tid = threadIdx.x;
  const int wid = tid >> 6, lane = tid & 63;
  const int fr = lane & 15, g = lane >> 4;
  const int wr = wid >> 2, wc = wid & 3;          // 2x4 wave grid; wave tile 128x64
  const int fswz = (fr & 7) << 4;
  // chunked XCD swizzle: xcd = blockIdx%8 owns contiguous bm chunk
  const int d = blockIdx.x;
  const int xcd = d & 7, l = d >> 3;
  const int bm = xcd * 8 + l / NBN, bn = l % NBN;
  const int m0 = bm << 8, n0 = bn << 8;
  const int which = n0 >> 10;                     // uniform per block
  const char* Ab = (const char*)(A + (size_t)m0 * 1024);
  const char* Bb = (const char*)(BtBase + (size_t)which * 1048576 + (size_t)(n0 & 1023) * 1024);

  // staging geometry: instr i in 0..3, LDS linear L = i*8192 + tid*16
  // row = i*64 + tid/8, col_byte = (tid&7)*16; source col pre-swizzled (involution)
  const int srow = tid >> 3;
  const int kb = ((tid & 7) << 4) ^ ((srow & 7) << 4);
  const char* aSrc = Ab + (size_t)srow * 2048 + kb;
  const char* bSrc = Bb + (size_t)srow * 2048 + kb;
  const int ldsOff = wid << 10;                   // wave-uniform byte base (+ lane*16 by HW)

#define STAGE_ALL(dstA, dstB, tt)                                             \
  do {                                                                        \
    _Pragma("unroll") for (int i = 0; i < 4; ++i)                             \
      gload_lds16(aSrc + (size_t)i * 131072 + (size_t)(tt) * 128,             \
                  (dstA) + i * 8192 + ldsOff);                                \
    _Pragma("unroll") for (int i = 0; i < 4; ++i)                             \
      gload_lds16(bSrc + (size_t)i * 131072 + (size_t)(tt) * 128,             \
                  (dstB) + i * 8192 + ldsOff);                                \
  } while (0)

#define AFRAG(mi, ks) (*(const s16x8*)(Acur + ((((wr) << 7) + (mi) * 16 + fr) << 7) + \
                                       ((((ks) << 6) | (g << 4)) ^ fswz)))
#define BFRAG(ni, ks) (*(const s16x8*)(Bcur + ((((wc) << 6) + (ni) * 16 + fr) << 7) + \
                                       ((((ks) << 6) | (g << 4)) ^ fswz)))

  f32x4 acc[8][4];
#pragma unroll
  for (int i = 0; i < 8; ++i)
#pragma unroll
    for (int j = 0; j < 4; ++j) acc[i][j] = (f32x4){0.f, 0.f, 0.f, 0.f};

  // prologue: stage K-tile 0 into slot 0
  STAGE_ALL((char*)&As[0][0], (char*)&Bs[0][0], 0);

#pragma unroll 2
  for (int t = 0; t < 16; ++t) {
    const int cur = t & 1;
    const char* Acur = (const char*)&As[cur][0];
    const char* Bcur = (const char*)&Bs[cur][0];

    // issue next tile's loads FIRST -> they have the whole compute phase to land
    if (t < 15) STAGE_ALL((char*)&As[cur ^ 1][0], (char*)&Bs[cur ^ 1][0], t + 1);

    if (t < 15) asm volatile("s_waitcnt vmcnt(8)" ::: "memory");   // tile t landed
    else        asm volatile("s_waitcnt vmcnt(0)" ::: "memory");
    __builtin_amdgcn_sched_barrier(0);
    __builtin_amdgcn_s_barrier();
    __builtin_amdgcn_s_setprio(1);

    // sub-phase 1: A rows 0-63 + all B cols; 32 MFMA
    s16x8 aF[2][4], bF0[2][2], bF1[2][2];
#pragma unroll
    for (int ks = 0; ks < 2; ++ks) {
#pragma unroll
      for (int mi = 0; mi < 4; ++mi) aF[ks][mi] = AFRAG(mi, ks);
#pragma unroll
      for (int ni = 0; ni < 2; ++ni) { bF0[ks][ni] = BFRAG(ni, ks); bF1[ks][ni] = BFRAG(2 + ni, ks); }
    }
#pragma unroll
    for (int ks = 0; ks < 2; ++ks)
#pragma unroll
      for (int mi = 0; mi < 4; ++mi)
#pragma unroll
        for (int ni = 0; ni < 2; ++ni) {
          acc[mi][ni]     = __builtin_amdgcn_mfma_f32_16x16x32_bf16(aF[ks][mi], bF0[ks][ni], acc[mi][ni], 0, 0, 0);
          acc[mi][2 + ni] = __builtin_amdgcn_mfma_f32_16x16x32_bf16(aF[ks][mi], bF1[ks][ni], acc[mi][2 + ni], 0, 0, 0);
        }

    // sub-phase 2: A rows 64-127 (reuse B frags); 32 MFMA
#pragma unroll
    for (int ks = 0; ks < 2; ++ks)
#pragma unroll
      for (int mi = 0; mi < 4; ++mi) aF[ks][mi] = AFRAG(4 + mi, ks);
#pragma unroll
    for (int ks = 0; ks < 2; ++ks)
#pragma unroll
      for (int mi = 0; mi < 4; ++mi)
#pragma unroll
        for (int ni = 0; ni < 2; ++ni) {
          acc[4 + mi][ni]     = __builtin_amdgcn_mfma_f32_16x16x32_bf16(aF[ks][mi], bF0[ks][ni], acc[4 + mi][ni], 0, 0, 0);
          acc[4 + mi][2 + ni] = __builtin_amdgcn_mfma_f32_16x16x32_bf16(aF[ks][mi], bF1[ks][ni], acc[4 + mi][2 + ni], 0, 0, 0);
        }

    __builtin_amdgcn_s_setprio(0);
    asm volatile("s_waitcnt lgkmcnt(0)" ::: "memory");  // reads done before buffer reuse
    __builtin_amdgcn_sched_barrier(0);
    __builtin_amdgcn_s_barrier();
  }
#undef STAGE_ALL
#undef AFRAG
#undef BFRAG

  // epilogue: D layout col=lane&15, row=(lane>>4)*4+reg  (m89-verified)
  const float* bb = (which == 0) ? b0 : (which == 1) ? b1 : b2;
  const int row0 = m0 + wr * 128 + (g << 2);
  const int col0 = n0 + wc * 64 + fr;
#pragma unroll
  for (int mi = 0; mi < 8; ++mi) {
#pragma unroll
    for (int ni = 0; ni < 4; ++ni) {
      const int c = col0 + ni * 16;
      const float bv = bb[c & 1023];
#pragma unroll
      for (int jj = 0; jj < 4; ++jj) {
        const int r = row0 + mi * 16 + jj;
        const float v = acc[mi][ni][jj] + bv;
        if (MODE == 2) {
          Oo[(size_t)r * 1024 + c] = v;
        } else {
          const int b = r >> 12, s = r & 4095;
          const int cl = c & 1023;
          const int h = cl >> 6, dh = cl & 63;
          short* ob = (which == 0) ? Qo : (which == 1) ? Ko : Vo;
          size_t addr;
          if (which < 2) addr = ((size_t)(b * 16 + h) * 4096 + s) * 64 + dh;
          else           addr = ((size_t)(b * 16 + h) * 64 + dh) * 4096 + s;
          ob[addr] = f2bf(v);
        }
      }
    }
  }
}

// ---------------- windowed causal attention ----------------
// grid = B*H*16 windows; block = 256 (4 waves); wave w owns q-rows [w*64, w*64+64)
__global__ __launch_bounds__(256) void attn_kernel(const short* __restrict__ Qg,
                                                   const short* __restrict__ Kg,
                                                   const short* __restrict__ Vg,
                                                   short* __restrict__ AO) {
  constexpr int S = 4096;
  __shared__ short Pl[4][16][272];  // per-wave P tile, padded
  const int tid = threadIdx.x;
  const int w = tid >> 6, lane = tid & 63;
  const int fr = lane & 15, g = lane >> 4;
  const int bhn = blockIdx.x;
  const int nb = bhn & 15, bh = bhn >> 4;
  const int b = bh >> 4, h = bh & 15;
  const short* Qb = Qg + ((size_t)bh * S + nb * 256) * 64;
  const short* Kb = Kg + ((size_t)bh * S + nb * 256) * 64;
  const short* Vb = Vg + (size_t)bh * 64 * S + nb * 256;

#pragma unroll
  for (int qi = 0; qi < 4; ++qi) {
    const int qrow = w * 64 + qi * 16;
    const int dmax = w * 4 + qi;  // diagonal 16-col tile index (tiles 0..dmax active)
    const s16x8 aq0 = *(const s16x8*)&Qb[(qrow + fr) * 64 + (g << 3)];
    const s16x8 aq1 = *(const s16x8*)&Qb[(qrow + fr) * 64 + 32 + (g << 3)];
    f32x4 sc[16];
#pragma unroll
    for (int i = 0; i < 16; ++i) sc[i] = (f32x4){0.f, 0.f, 0.f, 0.f};
#pragma unroll
    for (int kt = 0; kt < 16; ++kt) {
      if (kt <= dmax) {
        const s16x8 kf0 = *(const s16x8*)&Kb[(kt * 16 + fr) * 64 + (g << 3)];
        const s16x8 kf1 = *(const s16x8*)&Kb[(kt * 16 + fr) * 64 + 32 + (g << 3)];
        sc[kt] = __builtin_amdgcn_mfma_f32_16x16x32_bf16(aq0, kf0, sc[kt], 0, 0, 0);
        sc[kt] = __builtin_amdgcn_mfma_f32_16x16x32_bf16(aq1, kf1, sc[kt], 0, 0, 0);
      }
    }
    // scale + causal mask (diag tile only) + row max
    float mrow[4] = {-3e38f, -3e38f, -3e38f, -3e38f};
#pragma unroll
    for (int kt = 0; kt < 16; ++kt) {
      if (kt <= dmax) {
#pragma unroll
        for (int jj = 0; jj < 4; ++jj) {
          float v = sc[kt][jj] * 0.125f;
          if (kt == dmax && fr > (g << 2) + jj) v = -3e38f;
          sc[kt][jj] = v;
          mrow[jj] = fmaxf(mrow[jj], v);
        }
      }
    }
#pragma unroll
    for (int jj = 0; jj < 4; ++jj) mrow[jj] = rmax16(mrow[jj]);
    float lsum[4] = {0.f, 0.f, 0.f, 0.f};
#pragma unroll
    for (int kt = 0; kt < 16; ++kt) {
      if (kt <= dmax) {
#pragma unroll
        for (int jj = 0; jj < 4; ++jj) {
          const float p = __expf(sc[kt][jj] - mrow[jj]);
          sc[kt][jj] = p;
          lsum[jj] += p;
        }
      }
    }
#pragma unroll
    for (int jj = 0; jj < 4; ++jj) lsum[jj] = rsum16(lsum[jj]);
    // P -> LDS (D-layout scatter), zero-fill odd trailing tile for 32-wide PV chunks
#pragma unroll
    for (int kt = 0; kt < 16; ++kt) {
      if (kt <= dmax) {
#pragma unroll
        for (int jj = 0; jj < 4; ++jj)
          Pl[w][(g << 2) + jj][kt * 16 + fr] = f2bf(sc[kt][jj]);
      } else if (kt == dmax + 1 && ((dmax + 1) & 1)) {
#pragma unroll
        for (int jj = 0; jj < 4; ++jj) Pl[w][(g << 2) + jj][kt * 16 + fr] = 0;
      }
    }
    asm volatile("s_waitcnt lgkmcnt(0)" ::: "memory");
    // PV: O[64q x 64dh] = P * V, V read as Vt[dh][s] (contiguous 16B per lane)
    f32x4 o[4];
#pragma unroll
    for (int di = 0; di < 4; ++di) o[di] = (f32x4){0.f, 0.f, 0.f, 0.f};
    const int nks2 = (dmax + 2) >> 1;
#pragma unroll
    for (int ks2 = 0; ks2 < 8; ++ks2) {
      if (ks2 < nks2) {
        const s16x8 pa = *(const s16x8*)&Pl[w][fr][ks2 * 32 + (g << 3)];
#pragma unroll
        for (int di = 0; di < 4; ++di) {
          const s16x8 vf = *(const s16x8*)&Vb[(size_t)(di * 16 + fr) * S + ks2 * 32 + (g << 3)];
          o[di] = __builtin_amdgcn_mfma_f32_16x16x32_bf16(pa, vf, o[di], 0, 0, 0);
        }
      }
    }
    float inv[4];
#pragma unroll
    for (int jj = 0; jj < 4; ++jj) inv[jj] = 1.f / lsum[jj];
    const int sg = nb * 256 + qrow + (g << 2);
#pragma unroll
    for (int di = 0; di < 4; ++di) {
#pragma unroll
      for (int jj = 0; jj < 4; ++jj) {
        AO[((size_t)b * S + sg + jj) * 1024 + h * 64 + di * 16 + fr] =
            f2bf(o[di][jj] * inv[jj]);
      }
    }
  }
}

extern "C" void kernel_launch(void* const* d_in, const int* in_sizes, int n_in,
                              void* d_out, int out_size, void* d_ws, size_t ws_size,
                              hipStream_t stream) {
  const float* x  = (const float*)d_in[0];
  const float* Wq = (const float*)d_in[1];
  const float* bq = (const float*)d_in[2];
  const float* Wk = (const float*)d_in[3];
  const float* bk = (const float*)d_in[4];
  const float* Wv = (const float*)d_in[5];
  const float* bv = (const float*)d_in[6];
  const float* Wo = (const float*)d_in[7];
  const float* bo = (const float*)d_in[8];
  float* out = (float*)d_out;

  char* ws = (char*)d_ws;
  short* xb  = (short*)ws;                                   // 32 MB  bf16 x [16384,1024]
  short* Wt  = (short*)(ws + (size_t)33554432);              // 8 MB   Wt q/k/v/o [1024,1024] each
  short* Qb  = (short*)(ws + (size_t)33554432 + 8388608);    // 32 MB  [B,H,S,DH]
  short* Kb  = Qb + (size_t)16777216;                        // 32 MB  [B,H,S,DH]
  short* Vb  = Kb + (size_t)16777216;                        // 32 MB  [B,H,DH,S]
  short* AOb = Vb + (size_t)16777216;                        // 32 MB  [B*S, D]

  cvt_x<<<4096, 256, 0, stream>>>((const float4*)x, (s16x4*)xb, 16777216 / 4);
  cvt_wT<<<dim3(256, 4), 256, 0, stream>>>(Wq, Wk, Wv, Wo, Wt);

  // fused QKV: grid = 64 bm * 12 bn = 768 (%8==0)
  gemm9<12, 0><<<768, 512, 0, stream>>>(xb, Wt, bq, bk, bv, Qb, Kb, Vb, nullptr);

  attn_kernel<<<1024, 256, 0, stream>>>(Qb, Kb, Vb, AOb);

  // O projection: grid = 64 bm * 4 bn = 256 (%8==0)
  gemm9<4, 2><<<256, 512, 0, stream>>>(AOb, Wt + 3145728, bo, bo, bo,
                                       nullptr, nullptr, nullptr, out);
}

// Round 7
// 420.356 us; speedup vs baseline: 1.1457x; 1.0135x over previous
//
#include <hip/hip_runtime.h>
#include <hip/hip_bf16.h>

// CausalLocalAttention: B=4, S=4096, D=1024, H=16, DH=64, W=256 (16 windows)
// cvt_x -> cvt_wT -> gemm10<QKV fused, 256^2 8-phase m201-style> -> attn -> gemm10<O>

typedef __attribute__((ext_vector_type(4))) float f32x4;
typedef __attribute__((ext_vector_type(8))) short s16x8;
typedef __attribute__((ext_vector_type(4))) short s16x4;

__device__ __forceinline__ short f2bf(float f) {
  unsigned u = __float_as_uint(f);
  u += 0x7fffu + ((u >> 16) & 1u);   // RNE
  return (short)(u >> 16);
}

__device__ __forceinline__ void gload_lds16(const void* g, void* l) {
  __builtin_amdgcn_global_load_lds((const __attribute__((address_space(1))) void*)g,
                                   (__attribute__((address_space(3))) void*)l,
                                   16, 0, 0);
}

__device__ __forceinline__ float rmax16(float v) {
  v = fmaxf(v, __shfl_xor(v, 1, 64));
  v = fmaxf(v, __shfl_xor(v, 2, 64));
  v = fmaxf(v, __shfl_xor(v, 4, 64));
  v = fmaxf(v, __shfl_xor(v, 8, 64));
  return v;
}
__device__ __forceinline__ float rsum16(float v) {
  v += __shfl_xor(v, 1, 64);
  v += __shfl_xor(v, 2, 64);
  v += __shfl_xor(v, 4, 64);
  v += __shfl_xor(v, 8, 64);
  return v;
}

// ---------------- convert x (fp32 -> bf16) ----------------
__global__ void cvt_x(const float4* __restrict__ in, s16x4* __restrict__ out, int n4) {
  for (int i = blockIdx.x * 256 + threadIdx.x; i < n4; i += gridDim.x * 256) {
    float4 v = in[i];
    s16x4 o;
    o[0] = f2bf(v.x); o[1] = f2bf(v.y); o[2] = f2bf(v.z); o[3] = f2bf(v.w);
    out[i] = o;
  }
}

// ------------- convert + transpose weights: W[k][n] fp32 -> Wt[n][k] bf16 -------------
__global__ void cvt_wT(const float* __restrict__ W0, const float* __restrict__ W1,
                       const float* __restrict__ W2, const float* __restrict__ W3,
                       short* __restrict__ out) {
  __shared__ float tile[64][65];
  const float* W = (blockIdx.y == 0) ? W0 : (blockIdx.y == 1) ? W1 : (blockIdx.y == 2) ? W2 : W3;
  short* o = out + (size_t)blockIdx.y * (1024 * 1024);
  const int kt = (blockIdx.x >> 4) << 6, nt = (blockIdx.x & 15) << 6;
  const int tid = threadIdx.x;
#pragma unroll
  for (int i = 0; i < 16; ++i) {
    int lin = i * 256 + tid;
    int r = lin >> 6, c = lin & 63;
    tile[r][c] = W[(size_t)(kt + r) * 1024 + nt + c];
  }
  __syncthreads();
#pragma unroll
  for (int i = 0; i < 16; ++i) {
    int lin = i * 256 + tid;
    int r = lin >> 6, c = lin & 63;
    o[(size_t)(nt + r) * 1024 + kt + c] = f2bf(tile[c][r]);
  }
}

// ======== 256x256 GEMM, BK=64, 8 waves, m201-style 4-phase/K-tile ========
// LDS: 4 half-slots per operand ([dbuf*2+half][128x64]); 1 half-tile staged/phase
// (lead 6, order B0,B1,A0,A1 -> every stage lands only after its region's reads
// drained behind a barrier). vmcnt(4) once per tile BEFORE the tile-boundary
// barrier (per-wave wait + barrier = global visibility). Quadrants:
// q0 accLo*bF0 (12 rd) / q1 accLo*bF1 (4) / q2 accHi*bF1 (8) / q3 accHi*bF0 (0).
template <int NBN, int MODE>
__global__ __launch_bounds__(512, 2) void gemm10(const short* __restrict__ A,
                                                 const short* __restrict__ BtBase,
                                                 const float* __restrict__ b0,
                                                 const float* __restrict__ b1,
                                                 const float* __restrict__ b2,
                                                 short* __restrict__ Qo,
                                                 short* __restrict__ Ko,
                                                 short* __restrict__ Vo,
                                                 float* __restrict__ Oo) {
  __shared__ short As[4][8192];   // [(t&1)*2+half][128 rows x 64 k]  64 KB
  __shared__ short Bs[4][8192];   //                                  64 KB
  const int tid = threadIdx.x;
  const int wid = tid >> 6, lane = tid & 63;
  const int fr = lane & 15, g = lane >> 4;
  const int wr = wid >> 2, wc = wid & 3;        // 2x4 wave grid; wave tile 128x64
  const int fswz = (fr & 7) << 4;
  const int bro = (wc & 1) << 6;
  // chunked XCD swizzle
  const int d = blockIdx.x;
  const int xcd = d & 7, l = d >> 3;
  const int bm = xcd * 8 + l / NBN, bn = l % NBN;
  const int m0 = bm << 8, n0 = bn << 8;
  const int which = n0 >> 10;
  const char* Ab = (const char*)(A + (size_t)m0 * 1024);
  const char* Bb = (const char*)(BtBase + (size_t)which * 1048576 + (size_t)(n0 & 1023) * 1024);
  // staging: per half-tile 2 loads; thread covers row j*64+tid/8, col (tid&7)*16
  // source col pre-swizzled with (row&7)<<4 (involution with read-side XOR)
  const int srow = tid >> 3;
  const int kb = ((tid & 7) << 4) ^ ((srow & 7) << 4);
  const char* aSrcB = Ab + (size_t)srow * 2048 + kb;
  const char* bSrcB = Bb + (size_t)srow * 2048 + kb;
  const int ldsOff = wid << 10;                 // wave-uniform base (+ lane*16 by HW)

#define STAGE_HALF(tt, idx)                                                    \
  do {                                                                         \
    const char* sp_ = (((idx) >= 2) ? aSrcB : bSrcB) +                         \
                      (size_t)((idx) & 1) * 262144 + (size_t)(tt) * 128;       \
    char* dp_ = ((((idx) >= 2) ? (char*)&As[(((tt) & 1) << 1) | ((idx) & 1)][0]\
                               : (char*)&Bs[(((tt) & 1) << 1) | ((idx) & 1)][0]\
                 )) + ldsOff;                                                  \
    gload_lds16(sp_, dp_);                                                     \
    gload_lds16(sp_ + 131072, dp_ + 8192);                                     \
  } while (0)

#define BRD(ks) ((((ks) << 6) | (g << 4)) ^ fswz)
#define AFR(qh, mi, ks) (*(const s16x8*)(Acur + ((((qh) << 6) + (mi) * 16 + fr) << 7) + BRD(ks)))
#define BFR(ni, ks) (*(const s16x8*)(Bcur + ((bro + (ni) * 16 + fr) << 7) + BRD(ks)))

#define PH_MID()                                          \
  __builtin_amdgcn_s_barrier();                           \
  asm volatile("s_waitcnt lgkmcnt(0)" ::: "memory");      \
  __builtin_amdgcn_sched_barrier(0);                      \
  __builtin_amdgcn_s_setprio(1)

#define PH_END()                                          \
  __builtin_amdgcn_s_setprio(0);                          \
  __builtin_amdgcn_s_barrier()

  f32x4 acc[8][4];
#pragma unroll
  for (int i = 0; i < 8; ++i)
#pragma unroll
    for (int j = 0; j < 4; ++j) acc[i][j] = (f32x4){0.f, 0.f, 0.f, 0.f};

  // prologue: tile0 all halves + tile1 B halves (lead 6)
  STAGE_HALF(0, 0); STAGE_HALF(0, 1); STAGE_HALF(0, 2); STAGE_HALF(0, 3);
  STAGE_HALF(1, 0); STAGE_HALF(1, 1);
  asm volatile("s_waitcnt vmcnt(4)" ::: "memory");   // tile 0 landed
  __builtin_amdgcn_sched_barrier(0);
  __builtin_amdgcn_s_barrier();

#pragma unroll 2
  for (int t = 0; t < 16; ++t) {
    const char* Acur = (const char*)&As[((t & 1) << 1) | wr][0];
    const char* Bcur = (const char*)&Bs[((t & 1) << 1) | (wc >> 1)][0];
    s16x8 aF[2][4], bF0[2][2], bF1[2][2];

    // ---- q0: read aF(lo)+bF0; stage A-h0(t+1); acc[0..3][0..1] ----
#pragma unroll
    for (int ks = 0; ks < 2; ++ks) {
#pragma unroll
      for (int mi = 0; mi < 4; ++mi) aF[ks][mi] = AFR(0, mi, ks);
#pragma unroll
      for (int ni = 0; ni < 2; ++ni) bF0[ks][ni] = BFR(ni, ks);
    }
    if (t < 15) STAGE_HALF(t + 1, 2);
    PH_MID();
#pragma unroll
    for (int ks = 0; ks < 2; ++ks)
#pragma unroll
      for (int mi = 0; mi < 4; ++mi)
#pragma unroll
        for (int ni = 0; ni < 2; ++ni)
          acc[mi][ni] = __builtin_amdgcn_mfma_f32_16x16x32_bf16(aF[ks][mi], bF0[ks][ni], acc[mi][ni], 0, 0, 0);
    PH_END();

    // ---- q1: read bF1; stage A-h1(t+1); acc[0..3][2..3] ----
#pragma unroll
    for (int ks = 0; ks < 2; ++ks)
#pragma unroll
      for (int ni = 0; ni < 2; ++ni) bF1[ks][ni] = BFR(2 + ni, ks);
    if (t < 15) STAGE_HALF(t + 1, 3);
    PH_MID();
#pragma unroll
    for (int ks = 0; ks < 2; ++ks)
#pragma unroll
      for (int mi = 0; mi < 4; ++mi)
#pragma unroll
        for (int ni = 0; ni < 2; ++ni)
          acc[mi][2 + ni] = __builtin_amdgcn_mfma_f32_16x16x32_bf16(aF[ks][mi], bF1[ks][ni], acc[mi][2 + ni], 0, 0, 0);
    PH_END();

    // ---- q2: read aF(hi); stage B-h0(t+2); acc[4..7][2..3] ----
#pragma unroll
    for (int ks = 0; ks < 2; ++ks)
#pragma unroll
      for (int mi = 0; mi < 4; ++mi) aF[ks][mi] = AFR(1, mi, ks);
    if (t < 14) STAGE_HALF(t + 2, 0);
    PH_MID();
#pragma unroll
    for (int ks = 0; ks < 2; ++ks)
#pragma unroll
      for (int mi = 0; mi < 4; ++mi)
#pragma unroll
        for (int ni = 0; ni < 2; ++ni)
          acc[4 + mi][2 + ni] = __builtin_amdgcn_mfma_f32_16x16x32_bf16(aF[ks][mi], bF1[ks][ni], acc[4 + mi][2 + ni], 0, 0, 0);
    PH_END();

    // ---- q3: no reads; stage B-h1(t+2); acc[4..7][0..1]; tile-boundary vmcnt ----
    if (t < 14) STAGE_HALF(t + 2, 1);
    __builtin_amdgcn_s_barrier();
    __builtin_amdgcn_s_setprio(1);
#pragma unroll
    for (int ks = 0; ks < 2; ++ks)
#pragma unroll
      for (int mi = 0; mi < 4; ++mi)
#pragma unroll
        for (int ni = 0; ni < 2; ++ni)
          acc[4 + mi][ni] = __builtin_amdgcn_mfma_f32_16x16x32_bf16(aF[ks][mi], bF0[ks][ni], acc[4 + mi][ni], 0, 0, 0);
    __builtin_amdgcn_s_setprio(0);
    if (t < 14)       asm volatile("s_waitcnt vmcnt(4)" ::: "memory");  // tile t+1 landed
    else if (t == 14) asm volatile("s_waitcnt vmcnt(0)" ::: "memory");  // tile 15 landed
    __builtin_amdgcn_sched_barrier(0);
    __builtin_amdgcn_s_barrier();
  }
#undef STAGE_HALF
#undef BRD
#undef AFR
#undef BFR
#undef PH_MID
#undef PH_END

  // epilogue: D layout col=lane&15, row=(lane>>4)*4+reg  (m89-verified)
  const float* bb = (which == 0) ? b0 : (which == 1) ? b1 : b2;
  const int row0 = m0 + wr * 128 + (g << 2);
  const int col0 = n0 + wc * 64 + fr;
#pragma unroll
  for (int mi = 0; mi < 8; ++mi) {
#pragma unroll
    for (int ni = 0; ni < 4; ++ni) {
      const int c = col0 + ni * 16;
      const float bv = bb[c & 1023];
#pragma unroll
      for (int jj = 0; jj < 4; ++jj) {
        const int r = row0 + mi * 16 + jj;
        const float v = acc[mi][ni][jj] + bv;
        if (MODE == 2) {
          Oo[(size_t)r * 1024 + c] = v;
        } else {
          const int b = r >> 12, s = r & 4095;
          const int cl = c & 1023;
          const int h = cl >> 6, dh = cl & 63;
          short* ob = (which == 0) ? Qo : (which == 1) ? Ko : Vo;
          size_t addr;
          if (which < 2) addr = ((size_t)(b * 16 + h) * 4096 + s) * 64 + dh;
          else           addr = ((size_t)(b * 16 + h) * 64 + dh) * 4096 + s;
          ob[addr] = f2bf(v);
        }
      }
    }
  }
}

// ---------------- windowed causal attention ----------------
// grid = B*H*16 windows; block = 256 (4 waves); wave w owns q-rows [w*64, w*64+64)
__global__ __launch_bounds__(256) void attn_kernel(const short* __restrict__ Qg,
                                                   const short* __restrict__ Kg,
                                                   const short* __restrict__ Vg,
                                                   short* __restrict__ AO) {
  constexpr int S = 4096;
  __shared__ short Pl[4][16][272];  // per-wave P tile, padded
  const int tid = threadIdx.x;
  const int w = tid >> 6, lane = tid & 63;
  const int fr = lane & 15, g = lane >> 4;
  const int bhn = blockIdx.x;
  const int nb = bhn & 15, bh = bhn >> 4;
  const int b = bh >> 4, h = bh & 15;
  const short* Qb = Qg + ((size_t)bh * S + nb * 256) * 64;
  const short* Kb = Kg + ((size_t)bh * S + nb * 256) * 64;
  const short* Vb = Vg + (size_t)bh * 64 * S + nb * 256;

#pragma unroll
  for (int qi = 0; qi < 4; ++qi) {
    const int qrow = w * 64 + qi * 16;
    const int dmax = w * 4 + qi;  // diagonal 16-col tile index (tiles 0..dmax active)
    const s16x8 aq0 = *(const s16x8*)&Qb[(qrow + fr) * 64 + (g << 3)];
    const s16x8 aq1 = *(const s16x8*)&Qb[(qrow + fr) * 64 + 32 + (g << 3)];
    f32x4 sc[16];
#pragma unroll
    for (int i = 0; i < 16; ++i) sc[i] = (f32x4){0.f, 0.f, 0.f, 0.f};
#pragma unroll
    for (int kt = 0; kt < 16; ++kt) {
      if (kt <= dmax) {
        const s16x8 kf0 = *(const s16x8*)&Kb[(kt * 16 + fr) * 64 + (g << 3)];
        const s16x8 kf1 = *(const s16x8*)&Kb[(kt * 16 + fr) * 64 + 32 + (g << 3)];
        sc[kt] = __builtin_amdgcn_mfma_f32_16x16x32_bf16(aq0, kf0, sc[kt], 0, 0, 0);
        sc[kt] = __builtin_amdgcn_mfma_f32_16x16x32_bf16(aq1, kf1, sc[kt], 0, 0, 0);
      }
    }
    // scale + causal mask (diag tile only) + row max
    float mrow[4] = {-3e38f, -3e38f, -3e38f, -3e38f};
#pragma unroll
    for (int kt = 0; kt < 16; ++kt) {
      if (kt <= dmax) {
#pragma unroll
        for (int jj = 0; jj < 4; ++jj) {
          float v = sc[kt][jj] * 0.125f;
          if (kt == dmax && fr > (g << 2) + jj) v = -3e38f;
          sc[kt][jj] = v;
          mrow[jj] = fmaxf(mrow[jj], v);
        }
      }
    }
#pragma unroll
    for (int jj = 0; jj < 4; ++jj) mrow[jj] = rmax16(mrow[jj]);
    float lsum[4] = {0.f, 0.f, 0.f, 0.f};
#pragma unroll
    for (int kt = 0; kt < 16; ++kt) {
      if (kt <= dmax) {
#pragma unroll
        for (int jj = 0; jj < 4; ++jj) {
          const float p = __expf(sc[kt][jj] - mrow[jj]);
          sc[kt][jj] = p;
          lsum[jj] += p;
        }
      }
    }
#pragma unroll
    for (int jj = 0; jj < 4; ++jj) lsum[jj] = rsum16(lsum[jj]);
    // P -> LDS (D-layout scatter), zero-fill odd trailing tile for 32-wide PV chunks
#pragma unroll
    for (int kt = 0; kt < 16; ++kt) {
      if (kt <= dmax) {
#pragma unroll
        for (int jj = 0; jj < 4; ++jj)
          Pl[w][(g << 2) + jj][kt * 16 + fr] = f2bf(sc[kt][jj]);
      } else if (kt == dmax + 1 && ((dmax + 1) & 1)) {
#pragma unroll
        for (int jj = 0; jj < 4; ++jj) Pl[w][(g << 2) + jj][kt * 16 + fr] = 0;
      }
    }
    asm volatile("s_waitcnt lgkmcnt(0)" ::: "memory");
    // PV: O[64q x 64dh] = P * V, V read as Vt[dh][s] (contiguous 16B per lane)
    f32x4 o[4];
#pragma unroll
    for (int di = 0; di < 4; ++di) o[di] = (f32x4){0.f, 0.f, 0.f, 0.f};
    const int nks2 = (dmax + 2) >> 1;
#pragma unroll
    for (int ks2 = 0; ks2 < 8; ++ks2) {
      if (ks2 < nks2) {
        const s16x8 pa = *(const s16x8*)&Pl[w][fr][ks2 * 32 + (g << 3)];
#pragma unroll
        for (int di = 0; di < 4; ++di) {
          const s16x8 vf = *(const s16x8*)&Vb[(size_t)(di * 16 + fr) * S + ks2 * 32 + (g << 3)];
          o[di] = __builtin_amdgcn_mfma_f32_16x16x32_bf16(pa, vf, o[di], 0, 0, 0);
        }
      }
    }
    float inv[4];
#pragma unroll
    for (int jj = 0; jj < 4; ++jj) inv[jj] = 1.f / lsum[jj];
    const int sg = nb * 256 + qrow + (g << 2);
#pragma unroll
    for (int di = 0; di < 4; ++di) {
#pragma unroll
      for (int jj = 0; jj < 4; ++jj) {
        AO[((size_t)b * S + sg + jj) * 1024 + h * 64 + di * 16 + fr] =
            f2bf(o[di][jj] * inv[jj]);
      }
    }
  }
}

extern "C" void kernel_launch(void* const* d_in, const int* in_sizes, int n_in,
                              void* d_out, int out_size, void* d_ws, size_t ws_size,
                              hipStream_t stream) {
  const float* x  = (const float*)d_in[0];
  const float* Wq = (const float*)d_in[1];
  const float* bq = (const float*)d_in[2];
  const float* Wk = (const float*)d_in[3];
  const float* bk = (const float*)d_in[4];
  const float* Wv = (const float*)d_in[5];
  const float* bv = (const float*)d_in[6];
  const float* Wo = (const float*)d_in[7];
  const float* bo = (const float*)d_in[8];
  float* out = (float*)d_out;

  char* ws = (char*)d_ws;
  short* xb  = (short*)ws;                                   // 32 MB  bf16 x [16384,1024]
  short* Wt  = (short*)(ws + (size_t)33554432);              // 8 MB   Wt q/k/v/o [1024,1024] each
  short* Qb  = (short*)(ws + (size_t)33554432 + 8388608);    // 32 MB  [B,H,S,DH]
  short* Kb  = Qb + (size_t)16777216;                        // 32 MB  [B,H,S,DH]
  short* Vb  = Kb + (size_t)16777216;                        // 32 MB  [B,H,DH,S]
  short* AOb = Vb + (size_t)16777216;                        // 32 MB  [B*S, D]

  cvt_x<<<4096, 256, 0, stream>>>((const float4*)x, (s16x4*)xb, 16777216 / 4);
  cvt_wT<<<dim3(256, 4), 256, 0, stream>>>(Wq, Wk, Wv, Wo, Wt);

  // fused QKV: grid = 64 bm * 12 bn = 768 (%8==0)
  gemm10<12, 0><<<768, 512, 0, stream>>>(xb, Wt, bq, bk, bv, Qb, Kb, Vb, nullptr);

  attn_kernel<<<1024, 256, 0, stream>>>(Qb, Kb, Vb, AOb);

  // O projection: grid = 64 bm * 4 bn = 256 (%8==0)
  gemm10<4, 2><<<256, 512, 0, stream>>>(AOb, Wt + 3145728, bo, bo, bo,
                                        nullptr, nullptr, nullptr, out);
}